// Round 3
// baseline (779.319 us; speedup 1.0000x reference)
//
#include <hip/hip_runtime.h>

#define T_SEQ 2048
#define HID   4096
#define NQH   32
#define NKVH  8
#define HD    128
#define QKV_N 6144  // (32 + 2*8) * 128

typedef __attribute__((ext_vector_type(8))) __bf16 bf16x8;
typedef __attribute__((ext_vector_type(4))) float floatx4;

static __device__ __forceinline__ unsigned short f2bf(float f) {
  union { float f; unsigned u; } v; v.f = f;
  unsigned r = v.u + 0x7fffu + ((v.u >> 16) & 1u);  // RNE
  return (unsigned short)(r >> 16);
}
static __device__ __forceinline__ float bf2f(unsigned short u) {
  union { unsigned u; float f; } v; v.u = ((unsigned)u) << 16;
  return v.f;
}

// async global->LDS, 16B per lane; LDS dest = wave-uniform base + lane*16
static __device__ __forceinline__ void gld_lds16(const unsigned short* g, unsigned short* l) {
  __builtin_amdgcn_global_load_lds(
      (const __attribute__((address_space(1))) unsigned int*)g,
      (__attribute__((address_space(3))) unsigned int*)l, 16, 0, 0);
}

// ---------------- elementwise f32 -> bf16 cast ------------------------------
__global__ __launch_bounds__(256) void cast_f32_bf16(
    const float* __restrict__ in, unsigned short* __restrict__ out) {
  int i = (blockIdx.x * 256 + threadIdx.x) * 4;
  float4 v = *(const float4*)(in + i);
  ushort4 o;
  o.x = f2bf(v.x); o.y = f2bf(v.y); o.z = f2bf(v.z); o.w = f2bf(v.w);
  *(ushort4*)(out + i) = o;
}

// ---------------- f32 [R][C] -> bf16 [C][R] tiled transpose+cast ------------
__global__ __launch_bounds__(256) void transpose_f32_bf16(
    const float* __restrict__ in, unsigned short* __restrict__ out,
    int R, int C) {
  __shared__ unsigned short tile[64][65];
  const int c0 = blockIdx.x * 64, r0 = blockIdx.y * 64;
  const int tr = threadIdx.x >> 4;
  const int tc = (threadIdx.x & 15) * 4;
#pragma unroll
  for (int p = 0; p < 4; p++) {
    int r = tr + p * 16;
    float4 v = *(const float4*)(in + (size_t)(r0 + r) * C + c0 + tc);
    tile[r][tc] = f2bf(v.x); tile[r][tc + 1] = f2bf(v.y);
    tile[r][tc + 2] = f2bf(v.z); tile[r][tc + 3] = f2bf(v.w);
  }
  __syncthreads();
#pragma unroll
  for (int p = 0; p < 4; p++) {
    int c = tr + p * 16;
    ushort4 o;
    o.x = tile[tc][c]; o.y = tile[tc + 1][c]; o.z = tile[tc + 2][c]; o.w = tile[tc + 3][c];
    *(ushort4*)(out + (size_t)(c0 + c) * R + r0 + tc) = o;
  }
}

// ------------- C[M,N] = A[M,K] * Bt[N,K]^T, m97 structure -------------------
// global_load_lds width-16 staging into unpadded [128][32] LDS tiles.
__global__ __launch_bounds__(256) void gemm_bt(
    const unsigned short* __restrict__ A, const unsigned short* __restrict__ Bt,
    float* __restrict__ Cf, unsigned short* __restrict__ Cb,
    int M, int N, int K) {
  __shared__ unsigned short As[128][32];
  __shared__ unsigned short Bs[128][32];
  const int tid = threadIdx.x, lane = tid & 63, wv = tid >> 6;
  const int m0 = blockIdx.y * 128, n0 = blockIdx.x * 128;
  const int wm = (wv >> 1) * 64, wn = (wv & 1) * 64;
  const int quad = lane >> 4, mc = lane & 15;
  // staging geometry: wave wv covers rows [wv*32, wv*32+32)
  const int srow = wv * 32 + (lane >> 2);
  const int scol = (lane & 3) * 8;
  const unsigned short* gA = A + (size_t)(m0 + srow) * K + scol;
  const unsigned short* gB = Bt + (size_t)(n0 + srow) * K + scol;
  unsigned short* lA0 = &As[wv * 32][0];
  unsigned short* lA1 = &As[wv * 32 + 16][0];
  unsigned short* lB0 = &Bs[wv * 32][0];
  unsigned short* lB1 = &Bs[wv * 32 + 16][0];
  floatx4 acc[4][4] = {};
  for (int k0 = 0; k0 < K; k0 += 32) {
    gld_lds16(gA + k0, lA0);
    gld_lds16(gA + k0 + (size_t)16 * K, lA1);
    gld_lds16(gB + k0, lB0);
    gld_lds16(gB + k0 + (size_t)16 * K, lB1);
    __syncthreads();  // drains vmcnt -> LDS tiles complete
    bf16x8 af[4], bfr[4];
#pragma unroll
    for (int i = 0; i < 4; i++) af[i] = *(const bf16x8*)(&As[wm + i * 16 + mc][quad * 8]);
#pragma unroll
    for (int j = 0; j < 4; j++) bfr[j] = *(const bf16x8*)(&Bs[wn + j * 16 + mc][quad * 8]);
#pragma unroll
    for (int i = 0; i < 4; i++)
#pragma unroll
      for (int j = 0; j < 4; j++)
        acc[i][j] = __builtin_amdgcn_mfma_f32_16x16x32_bf16(af[i], bfr[j], acc[i][j], 0, 0, 0);
    __syncthreads();  // readers done before next iter's staging overwrites
  }
#pragma unroll
  for (int i = 0; i < 4; i++)
#pragma unroll
    for (int j = 0; j < 4; j++)
#pragma unroll
      for (int r = 0; r < 4; r++) {
        int row = m0 + wm + i * 16 + quad * 4 + r;
        int col = n0 + wn + j * 16 + mc;
        if (Cf) Cf[(size_t)row * N + col] = acc[i][j][r];
        else    Cb[(size_t)row * N + col] = f2bf(acc[i][j][r]);
      }
}

// ---------- fused per-head RMSNorm + RoPE; V copy + transpose to [kv][d][t] --
__global__ __launch_bounds__(64) void normrope_kernel(
    const unsigned short* __restrict__ qkv,
    const float* __restrict__ qw, const float* __restrict__ kw,
    unsigned short* __restrict__ qout, unsigned short* __restrict__ kout,
    unsigned short* __restrict__ vt) {
  const int t = blockIdx.x, hh = blockIdx.y, ln = threadIdx.x;
  const unsigned short* x = qkv + (size_t)t * QKV_N + hh * HD;
  if (hh >= NQH + NKVH) {  // V head: passthrough, transposed store
    int kvh = hh - (NQH + NKVH);
    vt[((size_t)kvh * HD + ln) * T_SEQ + t] = x[ln];
    vt[((size_t)kvh * HD + ln + 64) * T_SEQ + t] = x[ln + 64];
    return;
  }
  float x0 = bf2f(x[ln]), x1 = bf2f(x[ln + 64]);
  float ss = x0 * x0 + x1 * x1;
#pragma unroll
  for (int off = 32; off > 0; off >>= 1) ss += __shfl_xor(ss, off, 64);
  float rinv = rsqrtf(ss * (1.0f / 128.0f) + 1e-6f);
  const float* w = (hh < NQH) ? qw : kw;
  float y0 = x0 * rinv * w[ln];
  float y1 = x1 * rinv * w[ln + 64];
  float pos = (float)t;  // positions == arange(T)
  float inv_freq = expf(((float)ln) * (-13.815510557964274f / 64.0f));
  float ang = pos * inv_freq;
  float s, c;
  sincosf(ang, &s, &c);
  float o0 = y0 * c - y1 * s;
  float o1 = y1 * c + y0 * s;
  if (hh < NQH) {
    qout[((size_t)t * NQH + hh) * HD + ln] = f2bf(o0);
    qout[((size_t)t * NQH + hh) * HD + ln + 64] = f2bf(o1);
  } else {
    int kh = hh - NQH;
    kout[((size_t)t * NKVH + kh) * HD + ln] = f2bf(o0);
    kout[((size_t)t * NKVH + kh) * HD + ln + 64] = f2bf(o1);
  }
}

// ---------------- flash-style causal GQA attention (group-shared K/V) --------
// grid: (T/32 q-tiles, 8 kv-heads); block: 256 = 4 waves; wave wv = head kvh*4+wv,
// handles 32 q-rows. K/V LDS tiles are staged once per block, used by 4 heads.
__global__ __launch_bounds__(256, 3) void attn_kernel(
    const unsigned short* __restrict__ qb, const unsigned short* __restrict__ kb,
    const unsigned short* __restrict__ vt, unsigned short* __restrict__ aout) {
  __shared__ unsigned short Ks[64][136];     // 272B rows: 2-way alias (free)
  __shared__ unsigned short Vs[128][72];     // [d][s], 144B rows: 2-way (free)
  __shared__ unsigned short Ps[4][32][72];   // per-wave P round-trip
  const int q0 = blockIdx.x * 32;
  const int kvh = blockIdx.y;
  const int tid = threadIdx.x, lane = tid & 63, wv = tid >> 6;
  const int h = kvh * 4 + wv;                // Q head this wave owns
  const int quad = lane >> 4, mc = lane & 15;
  // Q fragments straight from global (one-time; no LDS)
  bf16x8 qf[2][4];
#pragma unroll
  for (int mi = 0; mi < 2; mi++)
#pragma unroll
    for (int kc = 0; kc < 4; kc++)
      qf[mi][kc] = *(const bf16x8*)(
          qb + ((size_t)(q0 + mi * 16 + mc) * NQH + h) * HD + kc * 32 + quad * 8);
  float m_i[2][4], l_i[2][4];
#pragma unroll
  for (int mi = 0; mi < 2; mi++)
#pragma unroll
    for (int r = 0; r < 4; r++) { m_i[mi][r] = -1e30f; l_i[mi][r] = 0.f; }
  floatx4 O[2][8] = {};
  const int ntiles = (q0 + 31) / 64 + 1;  // causal
  for (int it = 0; it < ntiles; it++) {
    const int s0 = it * 64;
    __syncthreads();  // previous iter's readers done
#pragma unroll
    for (int p = 0; p < 4; p++) {
      int flat = (p * 256 + tid) * 8;
      int r = flat >> 7, d = flat & 127;
      *(uint4*)(&Ks[r][d]) = *(const uint4*)(kb + ((size_t)(s0 + r) * NKVH + kvh) * HD + d);
    }
#pragma unroll
    for (int p = 0; p < 4; p++) {
      int flat = (p * 256 + tid) * 8;
      int d = flat >> 6, s = flat & 63;
      *(uint4*)(&Vs[d][s]) = *(const uint4*)(vt + ((size_t)kvh * HD + d) * T_SEQ + s0 + s);
    }
    __syncthreads();
    // S = Q K^T for this wave's 32 q-rows x 64 s-cols
    float S[2][4][4];
#pragma unroll
    for (int mi = 0; mi < 2; mi++)
#pragma unroll
      for (int jt = 0; jt < 4; jt++) {
        floatx4 acc = {};
#pragma unroll
        for (int kc = 0; kc < 4; kc++) {
          bf16x8 bfr = *(const bf16x8*)(&Ks[jt * 16 + mc][kc * 32 + quad * 8]);
          acc = __builtin_amdgcn_mfma_f32_16x16x32_bf16(qf[mi][kc], bfr, acc, 0, 0, 0);
        }
#pragma unroll
        for (int r = 0; r < 4; r++) {
          int qrow = q0 + mi * 16 + quad * 4 + r;
          int scol = s0 + jt * 16 + mc;
          float sv = acc[r] * 0.08838834764831845f;  // 1/sqrt(128)
          S[mi][jt][r] = (scol <= qrow) ? sv : -1e30f;
        }
      }
    // online softmax per q-row
#pragma unroll
    for (int mi = 0; mi < 2; mi++)
#pragma unroll
      for (int r = 0; r < 4; r++) {
        float mx = fmaxf(fmaxf(S[mi][0][r], S[mi][1][r]), fmaxf(S[mi][2][r], S[mi][3][r]));
#pragma unroll
        for (int off = 1; off < 16; off <<= 1) mx = fmaxf(mx, __shfl_xor(mx, off, 64));
        float mnew = fmaxf(m_i[mi][r], mx);
        float alpha = __expf(m_i[mi][r] - mnew);
        float rs = 0.f;
#pragma unroll
        for (int jt = 0; jt < 4; jt++) {
          float pv = __expf(S[mi][jt][r] - mnew);
          S[mi][jt][r] = pv;
          rs += pv;
        }
#pragma unroll
        for (int off = 1; off < 16; off <<= 1) rs += __shfl_xor(rs, off, 64);
        m_i[mi][r] = mnew;
        l_i[mi][r] = l_i[mi][r] * alpha + rs;
#pragma unroll
        for (int jd = 0; jd < 8; jd++) O[mi][jd][r] *= alpha;
      }
    // P: C-layout -> LDS (wave-private) -> A-layout
#pragma unroll
    for (int mi = 0; mi < 2; mi++)
#pragma unroll
      for (int jt = 0; jt < 4; jt++)
#pragma unroll
        for (int r = 0; r < 4; r++)
          Ps[wv][mi * 16 + quad * 4 + r][jt * 16 + mc] = f2bf(S[mi][jt][r]);
    bf16x8 pa[2][2];
#pragma unroll
    for (int mi = 0; mi < 2; mi++)
#pragma unroll
      for (int kb2 = 0; kb2 < 2; kb2++)
        pa[mi][kb2] = *(const bf16x8*)(&Ps[wv][mi * 16 + mc][kb2 * 32 + quad * 8]);
#pragma unroll
    for (int jd = 0; jd < 8; jd++) {
      bf16x8 vb0 = *(const bf16x8*)(&Vs[jd * 16 + mc][quad * 8]);
      bf16x8 vb1 = *(const bf16x8*)(&Vs[jd * 16 + mc][32 + quad * 8]);
#pragma unroll
      for (int mi = 0; mi < 2; mi++) {
        O[mi][jd] = __builtin_amdgcn_mfma_f32_16x16x32_bf16(pa[mi][0], vb0, O[mi][jd], 0, 0, 0);
        O[mi][jd] = __builtin_amdgcn_mfma_f32_16x16x32_bf16(pa[mi][1], vb1, O[mi][jd], 0, 0, 0);
      }
    }
  }
#pragma unroll
  for (int mi = 0; mi < 2; mi++)
#pragma unroll
    for (int jd = 0; jd < 8; jd++)
#pragma unroll
      for (int r = 0; r < 4; r++) {
        int qrow = q0 + mi * 16 + quad * 4 + r;
        float val = O[mi][jd][r] / l_i[mi][r];
        aout[(size_t)qrow * (NQH * HD) + h * HD + jd * 16 + mc] = f2bf(val);
      }
}

extern "C" void kernel_launch(void* const* d_in, const int* in_sizes, int n_in,
                              void* d_out, int out_size, void* d_ws, size_t ws_size,
                              hipStream_t stream) {
  const float* hidden    = (const float*)d_in[1];  // f32 [2048][4096]
  const float* w_qkv     = (const float*)d_in[2];  // f32 [4096][6144]
  const float* q_norm    = (const float*)d_in[3];  // f32 [128]
  const float* k_norm    = (const float*)d_in[4];  // f32 [128]
  const float* w_o       = (const float*)d_in[5];  // f32 [4096][4096]
  float* out             = (float*)d_out;          // f32 [2048][4096]
  char* ws = (char*)d_ws;
  // Workspace plan (total 92,274,688 B):
  //  [0 .. 50,331,648): wqkv_t bf16 [6144][4096]; dead after gemm1 -> reused for
  //                     q_bf/k_bf/v_t/attn.
  //  [50,331,648 .. 75,497,472): qkv_bf bf16 [2048][6144]; dead after normrope.
  //  [75,497,472 .. 92,274,688): hidden_bf bf16 [2048][4096]; dead after gemm1.
  //  wo_t bf16 [4096][4096] @50,331,648 overlays the two dead regions; its
  //  transpose is launched AFTER normrope.
  unsigned short* wqkv_t   = (unsigned short*)(ws);
  unsigned short* q_bf     = (unsigned short*)(ws);               // [2048][32][128]
  unsigned short* k_bf     = (unsigned short*)(ws + 16777216);    // [2048][8][128]
  unsigned short* v_t      = (unsigned short*)(ws + 20971520);    // [8][128][2048]
  unsigned short* attn     = (unsigned short*)(ws + 25165824);    // [2048][4096]
  unsigned short* qkv_bf   = (unsigned short*)(ws + 50331648);    // [2048][6144]
  unsigned short* wo_t     = (unsigned short*)(ws + 50331648);    // [4096][4096]
  unsigned short* hidden_b = (unsigned short*)(ws + 75497472);    // [2048][4096]

  cast_f32_bf16<<<dim3((T_SEQ * HID) / 1024), 256, 0, stream>>>(hidden, hidden_b);
  transpose_f32_bf16<<<dim3(QKV_N / 64, HID / 64), 256, 0, stream>>>(w_qkv, wqkv_t, HID, QKV_N);
  gemm_bt<<<dim3(QKV_N / 128, T_SEQ / 128), 256, 0, stream>>>(
      hidden_b, wqkv_t, nullptr, qkv_bf, T_SEQ, QKV_N, HID);
  normrope_kernel<<<dim3(T_SEQ, NQH + 2 * NKVH), 64, 0, stream>>>(
      qkv_bf, q_norm, k_norm, q_bf, k_bf, v_t);
  transpose_f32_bf16<<<dim3(HID / 64, HID / 64), 256, 0, stream>>>(w_o, wo_t, HID, HID);
  attn_kernel<<<dim3(T_SEQ / 32, NKVH), 256, 0, stream>>>(q_bf, k_bf, v_t, attn);
  gemm_bt<<<dim3(HID / 128, T_SEQ / 128), 256, 0, stream>>>(
      attn, wo_t, out, nullptr, T_SEQ, HID, HID);
}

// Round 4
// 657.627 us; speedup vs baseline: 1.1850x; 1.1850x over previous
//
#include <hip/hip_runtime.h>

#define T_SEQ 2048
#define HID   4096
#define NQH   32
#define NKVH  8
#define HD    128
#define QKV_N 6144  // (32 + 2*8) * 128

typedef __attribute__((ext_vector_type(8))) __bf16 bf16x8;
typedef __attribute__((ext_vector_type(4))) float floatx4;

static __device__ __forceinline__ unsigned short f2bf(float f) {
  union { float f; unsigned u; } v; v.f = f;
  unsigned r = v.u + 0x7fffu + ((v.u >> 16) & 1u);  // RNE
  return (unsigned short)(r >> 16);
}
static __device__ __forceinline__ float bf2f(unsigned short u) {
  union { unsigned u; float f; } v; v.u = ((unsigned)u) << 16;
  return v.f;
}

// async global->LDS, 16B per lane; LDS dest = wave-uniform base + lane*16
static __device__ __forceinline__ void gld_lds16(const unsigned short* g, unsigned short* l) {
  __builtin_amdgcn_global_load_lds(
      (const __attribute__((address_space(1))) unsigned int*)g,
      (__attribute__((address_space(3))) unsigned int*)l, 16, 0, 0);
}

// ---------------- elementwise f32 -> bf16 cast ------------------------------
__global__ __launch_bounds__(256) void cast_f32_bf16(
    const float* __restrict__ in, unsigned short* __restrict__ out) {
  int i = (blockIdx.x * 256 + threadIdx.x) * 4;
  float4 v = *(const float4*)(in + i);
  ushort4 o;
  o.x = f2bf(v.x); o.y = f2bf(v.y); o.z = f2bf(v.z); o.w = f2bf(v.w);
  *(ushort4*)(out + i) = o;
}

// ---------------- f32 [R][C] -> bf16 [C][R] tiled transpose+cast ------------
__global__ __launch_bounds__(256) void transpose_f32_bf16(
    const float* __restrict__ in, unsigned short* __restrict__ out,
    int R, int C) {
  __shared__ unsigned short tile[64][65];
  const int c0 = blockIdx.x * 64, r0 = blockIdx.y * 64;
  const int tr = threadIdx.x >> 4;
  const int tc = (threadIdx.x & 15) * 4;
#pragma unroll
  for (int p = 0; p < 4; p++) {
    int r = tr + p * 16;
    float4 v = *(const float4*)(in + (size_t)(r0 + r) * C + c0 + tc);
    tile[r][tc] = f2bf(v.x); tile[r][tc + 1] = f2bf(v.y);
    tile[r][tc + 2] = f2bf(v.z); tile[r][tc + 3] = f2bf(v.w);
  }
  __syncthreads();
#pragma unroll
  for (int p = 0; p < 4; p++) {
    int c = tr + p * 16;
    ushort4 o;
    o.x = tile[tc][c]; o.y = tile[tc + 1][c]; o.z = tile[tc + 2][c]; o.w = tile[tc + 3][c];
    *(ushort4*)(out + (size_t)(c0 + c) * R + r0 + tc) = o;
  }
}

// ------------- C[M,N] = A[M,K] * Bt[N,K]^T, m97 structure -------------------
__global__ __launch_bounds__(256) void gemm_bt(
    const unsigned short* __restrict__ A, const unsigned short* __restrict__ Bt,
    float* __restrict__ Cf, unsigned short* __restrict__ Cb,
    int M, int N, int K) {
  __shared__ unsigned short As[128][32];
  __shared__ unsigned short Bs[128][32];
  const int tid = threadIdx.x, lane = tid & 63, wv = tid >> 6;
  const int m0 = blockIdx.y * 128, n0 = blockIdx.x * 128;
  const int wm = (wv >> 1) * 64, wn = (wv & 1) * 64;
  const int quad = lane >> 4, mc = lane & 15;
  const int srow = wv * 32 + (lane >> 2);
  const int scol = (lane & 3) * 8;
  const unsigned short* gA = A + (size_t)(m0 + srow) * K + scol;
  const unsigned short* gB = Bt + (size_t)(n0 + srow) * K + scol;
  unsigned short* lA0 = &As[wv * 32][0];
  unsigned short* lA1 = &As[wv * 32 + 16][0];
  unsigned short* lB0 = &Bs[wv * 32][0];
  unsigned short* lB1 = &Bs[wv * 32 + 16][0];
  floatx4 acc[4][4] = {};
  for (int k0 = 0; k0 < K; k0 += 32) {
    gld_lds16(gA + k0, lA0);
    gld_lds16(gA + k0 + (size_t)16 * K, lA1);
    gld_lds16(gB + k0, lB0);
    gld_lds16(gB + k0 + (size_t)16 * K, lB1);
    __syncthreads();
    bf16x8 af[4], bfr[4];
#pragma unroll
    for (int i = 0; i < 4; i++) af[i] = *(const bf16x8*)(&As[wm + i * 16 + mc][quad * 8]);
#pragma unroll
    for (int j = 0; j < 4; j++) bfr[j] = *(const bf16x8*)(&Bs[wn + j * 16 + mc][quad * 8]);
#pragma unroll
    for (int i = 0; i < 4; i++)
#pragma unroll
      for (int j = 0; j < 4; j++)
        acc[i][j] = __builtin_amdgcn_mfma_f32_16x16x32_bf16(af[i], bfr[j], acc[i][j], 0, 0, 0);
    __syncthreads();
  }
#pragma unroll
  for (int i = 0; i < 4; i++)
#pragma unroll
    for (int j = 0; j < 4; j++)
#pragma unroll
      for (int r = 0; r < 4; r++) {
        int row = m0 + wm + i * 16 + quad * 4 + r;
        int col = n0 + wn + j * 16 + mc;
        if (Cf) Cf[(size_t)row * N + col] = acc[i][j][r];
        else    Cb[(size_t)row * N + col] = f2bf(acc[i][j][r]);
      }
}

// ---------- fused per-head RMSNorm + RoPE; V copy + transpose to [kv][d][t] --
__global__ __launch_bounds__(64) void normrope_kernel(
    const unsigned short* __restrict__ qkv,
    const float* __restrict__ qw, const float* __restrict__ kw,
    unsigned short* __restrict__ qout, unsigned short* __restrict__ kout,
    unsigned short* __restrict__ vt) {
  const int t = blockIdx.x, hh = blockIdx.y, ln = threadIdx.x;
  const unsigned short* x = qkv + (size_t)t * QKV_N + hh * HD;
  if (hh >= NQH + NKVH) {
    int kvh = hh - (NQH + NKVH);
    vt[((size_t)kvh * HD + ln) * T_SEQ + t] = x[ln];
    vt[((size_t)kvh * HD + ln + 64) * T_SEQ + t] = x[ln + 64];
    return;
  }
  float x0 = bf2f(x[ln]), x1 = bf2f(x[ln + 64]);
  float ss = x0 * x0 + x1 * x1;
#pragma unroll
  for (int off = 32; off > 0; off >>= 1) ss += __shfl_xor(ss, off, 64);
  float rinv = rsqrtf(ss * (1.0f / 128.0f) + 1e-6f);
  const float* w = (hh < NQH) ? qw : kw;
  float y0 = x0 * rinv * w[ln];
  float y1 = x1 * rinv * w[ln + 64];
  float pos = (float)t;  // positions == arange(T)
  float inv_freq = expf(((float)ln) * (-13.815510557964274f / 64.0f));
  float ang = pos * inv_freq;
  float s, c;
  sincosf(ang, &s, &c);
  float o0 = y0 * c - y1 * s;
  float o1 = y1 * c + y0 * s;
  if (hh < NQH) {
    qout[((size_t)t * NQH + hh) * HD + ln] = f2bf(o0);
    qout[((size_t)t * NQH + hh) * HD + ln + 64] = f2bf(o1);
  } else {
    int kh = hh - NQH;
    kout[((size_t)t * NKVH + kh) * HD + ln] = f2bf(o0);
    kout[((size_t)t * NKVH + kh) * HD + ln + 64] = f2bf(o1);
  }
}

// ---------------- causal GQA attention, no-online-softmax --------------------
// RMSNorm bounds |score| <= sqrt(128) = 11.32, so exp(s) <= 8.2e4 and
// l <= 2048*8.2e4 = 1.7e8: direct exp2 accumulation is f32/bf16-safe.
// grid: (T/32 q-tiles swizzled, 8 kv-heads); block 256 = 4 waves; wave wv =
// head kvh*4+wv over 32 q-rows. Row-sum l accumulated via MFMA w/ ones-B.
__global__ __launch_bounds__(256, 3) void attn_kernel(
    const unsigned short* __restrict__ qb, const unsigned short* __restrict__ kb,
    const unsigned short* __restrict__ vt, unsigned short* __restrict__ aout) {
  __shared__ unsigned short smem[27136];      // 54272 B total -> 3 blocks/CU
  unsigned short* Ks = smem;                  // [64][136]  272B rows
  unsigned short* Vs = smem + 8704;           // [128][72]  144B rows
  unsigned short* Ps = smem + 17920;          // [4][32][72] per-wave P
  const int bx = blockIdx.x;
  const int qt = (bx & 1) ? (63 - (bx >> 1)) : (bx >> 1);  // long/short mix
  const int q0 = qt * 32;
  const int kvh = blockIdx.y;
  const int tid = threadIdx.x, lane = tid & 63, wv = tid >> 6;
  const int h = kvh * 4 + wv;
  const int quad = lane >> 4, mc = lane & 15;
  const float c2 = 0.1275356394f;  // log2(e)/sqrt(128)
  const __bf16 one = (__bf16)1.0f;
  const bf16x8 ones = {one, one, one, one, one, one, one, one};
  bf16x8 qf[2][4];
#pragma unroll
  for (int mi = 0; mi < 2; mi++)
#pragma unroll
    for (int kc = 0; kc < 4; kc++)
      qf[mi][kc] = *(const bf16x8*)(
          qb + ((size_t)(q0 + mi * 16 + mc) * NQH + h) * HD + kc * 32 + quad * 8);
  floatx4 O[2][8] = {};
  floatx4 lac[2] = {};
  const int ntiles = (qt >> 1) + 1;
  for (int it = 0; it < ntiles; it++) {
    const int s0 = it * 64;
    __syncthreads();  // prev iter readers done
#pragma unroll
    for (int p = 0; p < 4; p++) {
      int flat = (p * 256 + tid) * 8;
      int r = flat >> 7, d = flat & 127;
      *(uint4*)(Ks + r * 136 + d) = *(const uint4*)(kb + ((size_t)(s0 + r) * NKVH + kvh) * HD + d);
    }
#pragma unroll
    for (int p = 0; p < 4; p++) {
      int flat = (p * 256 + tid) * 8;
      int d = flat >> 6, s = flat & 63;
      *(uint4*)(Vs + d * 72 + s) = *(const uint4*)(vt + ((size_t)kvh * HD + d) * T_SEQ + s0 + s);
    }
    __syncthreads();
    // S = Q K^T -> p = exp2(S*c2) masked -> Ps (A-layout round trip)
#pragma unroll
    for (int jt = 0; jt < 4; jt++) {
      bf16x8 bfr[4];
#pragma unroll
      for (int kc = 0; kc < 4; kc++)
        bfr[kc] = *(const bf16x8*)(Ks + (jt * 16 + mc) * 136 + kc * 32 + quad * 8);
#pragma unroll
      for (int mi = 0; mi < 2; mi++) {
        floatx4 acc = {};
#pragma unroll
        for (int kc = 0; kc < 4; kc++)
          acc = __builtin_amdgcn_mfma_f32_16x16x32_bf16(qf[mi][kc], bfr[kc], acc, 0, 0, 0);
        int qrow = q0 + mi * 16 + quad * 4;
        int scol = s0 + jt * 16 + mc;
#pragma unroll
        for (int r = 0; r < 4; r++) {
          float p = (scol <= qrow + r) ? exp2f(acc[r] * c2) : 0.f;
          Ps[(size_t)(wv * 32 + mi * 16 + quad * 4 + r) * 72 + jt * 16 + mc] = f2bf(p);
        }
      }
    }
    // P A-frags (in-wave DS ordering; Ps region is wave-private)
    bf16x8 pa[2][2];
#pragma unroll
    for (int mi = 0; mi < 2; mi++)
#pragma unroll
      for (int kb2 = 0; kb2 < 2; kb2++)
        pa[mi][kb2] = *(const bf16x8*)(Ps + (size_t)(wv * 32 + mi * 16 + mc) * 72 + kb2 * 32 + quad * 8);
    // row-sum l via MFMA with ones-B (no shuffles)
#pragma unroll
    for (int mi = 0; mi < 2; mi++) {
      lac[mi] = __builtin_amdgcn_mfma_f32_16x16x32_bf16(pa[mi][0], ones, lac[mi], 0, 0, 0);
      lac[mi] = __builtin_amdgcn_mfma_f32_16x16x32_bf16(pa[mi][1], ones, lac[mi], 0, 0, 0);
    }
    // O += P V
#pragma unroll
    for (int jd = 0; jd < 8; jd++) {
      bf16x8 vb0 = *(const bf16x8*)(Vs + (jd * 16 + mc) * 72 + quad * 8);
      bf16x8 vb1 = *(const bf16x8*)(Vs + (jd * 16 + mc) * 72 + 32 + quad * 8);
#pragma unroll
      for (int mi = 0; mi < 2; mi++) {
        O[mi][jd] = __builtin_amdgcn_mfma_f32_16x16x32_bf16(pa[mi][0], vb0, O[mi][jd], 0, 0, 0);
        O[mi][jd] = __builtin_amdgcn_mfma_f32_16x16x32_bf16(pa[mi][1], vb1, O[mi][jd], 0, 0, 0);
      }
    }
  }
  // coalesced epilogue: stage O/l via LDS (reuse whole smem), 16B stores
  __syncthreads();
  float rl[2][4];
#pragma unroll
  for (int mi = 0; mi < 2; mi++)
#pragma unroll
    for (int r = 0; r < 4; r++) rl[mi][r] = 1.0f / lac[mi][r];
#pragma unroll
  for (int mi = 0; mi < 2; mi++)
#pragma unroll
    for (int jd = 0; jd < 8; jd++)
#pragma unroll
      for (int r = 0; r < 4; r++)
        smem[(size_t)(wv * 32 + mi * 16 + quad * 4 + r) * 128 + jd * 16 + mc] =
            f2bf(O[mi][jd][r] * rl[mi][r]);
  __syncthreads();
  const int rr = tid >> 1;            // 0..127: wave wv' = rr>>5, q-row rr&31
  const int cb = (tid & 1) * 64;
  const size_t gbase = (size_t)(q0 + (rr & 31)) * (NQH * HD) + (kvh * 4 + (rr >> 5)) * HD + cb;
#pragma unroll
  for (int i = 0; i < 8; i++) {
    uint4 v = *(const uint4*)(smem + (size_t)rr * 128 + cb + i * 8);
    *(uint4*)(aout + gbase + i * 8) = v;
  }
}

extern "C" void kernel_launch(void* const* d_in, const int* in_sizes, int n_in,
                              void* d_out, int out_size, void* d_ws, size_t ws_size,
                              hipStream_t stream) {
  const float* hidden    = (const float*)d_in[1];  // f32 [2048][4096]
  const float* w_qkv     = (const float*)d_in[2];  // f32 [4096][6144]
  const float* q_norm    = (const float*)d_in[3];  // f32 [128]
  const float* k_norm    = (const float*)d_in[4];  // f32 [128]
  const float* w_o       = (const float*)d_in[5];  // f32 [4096][4096]
  float* out             = (float*)d_out;          // f32 [2048][4096]
  char* ws = (char*)d_ws;
  unsigned short* wqkv_t   = (unsigned short*)(ws);
  unsigned short* q_bf     = (unsigned short*)(ws);               // [2048][32][128]
  unsigned short* k_bf     = (unsigned short*)(ws + 16777216);    // [2048][8][128]
  unsigned short* v_t      = (unsigned short*)(ws + 20971520);    // [8][128][2048]
  unsigned short* attn     = (unsigned short*)(ws + 25165824);    // [2048][4096]
  unsigned short* qkv_bf   = (unsigned short*)(ws + 50331648);    // [2048][6144]
  unsigned short* wo_t     = (unsigned short*)(ws + 50331648);    // [4096][4096]
  unsigned short* hidden_b = (unsigned short*)(ws + 75497472);    // [2048][4096]

  cast_f32_bf16<<<dim3((T_SEQ * HID) / 1024), 256, 0, stream>>>(hidden, hidden_b);
  transpose_f32_bf16<<<dim3(QKV_N / 64, HID / 64), 256, 0, stream>>>(w_qkv, wqkv_t, HID, QKV_N);
  gemm_bt<<<dim3(QKV_N / 128, T_SEQ / 128), 256, 0, stream>>>(
      hidden_b, wqkv_t, nullptr, qkv_bf, T_SEQ, QKV_N, HID);
  normrope_kernel<<<dim3(T_SEQ, NQH + 2 * NKVH), 64, 0, stream>>>(
      qkv_bf, q_norm, k_norm, q_bf, k_bf, v_t);
  transpose_f32_bf16<<<dim3(HID / 64, HID / 64), 256, 0, stream>>>(w_o, wo_t, HID, HID);
  attn_kernel<<<dim3(T_SEQ / 32, NKVH), 256, 0, stream>>>(q_bf, k_bf, v_t, attn);
  gemm_bt<<<dim3(HID / 128, T_SEQ / 128), 256, 0, stream>>>(
      attn, wo_t, out, nullptr, T_SEQ, HID, HID);
}